// Round 1
// baseline (1119.487 us; speedup 1.0000x reference)
//
#include <hip/hip_runtime.h>
#include <math.h>

#define BATCH 256
#define TSTEPS 1024
#define DIN 64
#define HID 100
#define GATES 400      // 4*HID
#define BLOCK 512
#define XT 32          // timesteps per x LDS tile

__global__ __launch_bounds__(BLOCK, 2)
void lstm_fused_kernel(const float* __restrict__ x, const float* __restrict__ h0,
                       const float* __restrict__ c0, const float* __restrict__ W_ih,
                       const float* __restrict__ W_hh, const float* __restrict__ b_ih,
                       const float* __restrict__ b_hh, const float* __restrict__ W_fc,
                       const float* __restrict__ b_fc, float* __restrict__ out)
{
    __shared__ __align__(16) float h_buf[2][104];   // double-buffered hidden state
    __shared__ __align__(16) float x_tile[XT * DIN];
    __shared__ float red[128];

    const int tid = threadIdx.x;
    const int b = blockIdx.x;
    const int q = tid & 3;        // gate type: 0=i 1=f 2=g 3=o
    const int n = tid >> 2;       // unit index (tid<400)
    const bool gate_thread = (tid < GATES);
    const int g = q * HID + n;    // row in W_ih / W_hh

    // ---- register-resident weights: W_ih row (64) + W_hh row (100) ----
    float wih[DIN];
    float whh[HID];
    float bias = 0.f;
    if (gate_thread) {
        const float4* wi4 = reinterpret_cast<const float4*>(W_ih + g * DIN);
        #pragma unroll
        for (int k = 0; k < DIN / 4; ++k) {
            float4 v = wi4[k];
            wih[4*k+0] = v.x; wih[4*k+1] = v.y; wih[4*k+2] = v.z; wih[4*k+3] = v.w;
        }
        const float4* wh4 = reinterpret_cast<const float4*>(W_hh + g * HID);
        #pragma unroll
        for (int k = 0; k < HID / 4; ++k) {
            float4 v = wh4[k];
            whh[4*k+0] = v.x; whh[4*k+1] = v.y; whh[4*k+2] = v.z; whh[4*k+3] = v.w;
        }
        bias = b_ih[g] + b_hh[g];
    }

    // ---- init h, c ----
    if (tid < HID) h_buf[0][tid] = h0[b * HID + tid];
    float c = 0.f;
    if (gate_thread && q == 0) c = c0[b * HID + n];
    __syncthreads();

    for (int t = 0; t < TSTEPS; ++t) {
        if ((t & (XT - 1)) == 0) {
            // stage next 32 timesteps of x: 2048 floats = 512 float4, one per thread
            const float4* xs = reinterpret_cast<const float4*>(
                x + (size_t)b * TSTEPS * DIN + (size_t)t * DIN);
            reinterpret_cast<float4*>(x_tile)[tid] = xs[tid];
            __syncthreads();
        }
        const int cur = t & 1, nxt = cur ^ 1;

        if (gate_thread) {
            float a0 = 0.f, a1 = 0.f, a2 = 0.f, a3 = 0.f;
            const float4* h4 = reinterpret_cast<const float4*>(h_buf[cur]);
            #pragma unroll
            for (int k = 0; k < HID / 4; ++k) {
                float4 hv = h4[k];
                a0 += hv.x * whh[4*k+0];
                a1 += hv.y * whh[4*k+1];
                a2 += hv.z * whh[4*k+2];
                a3 += hv.w * whh[4*k+3];
            }
            const float4* x4 = reinterpret_cast<const float4*>(&x_tile[(t & (XT - 1)) * DIN]);
            #pragma unroll
            for (int k = 0; k < DIN / 4; ++k) {
                float4 xv = x4[k];
                a0 += xv.x * wih[4*k+0];
                a1 += xv.y * wih[4*k+1];
                a2 += xv.z * wih[4*k+2];
                a3 += xv.w * wih[4*k+3];
            }
            float z = ((a0 + a1) + (a2 + a3)) + bias;

            // activation: q==2 -> tanh, else sigmoid (branchless-ish; q is per-thread const)
            float zq = (q == 2) ? 2.f * z : z;
            float e = __expf(-zq);
            float s = 1.f / (1.f + e);
            float a = (q == 2) ? (2.f * s - 1.f) : s;

            // quad exchange: lane 4n gathers f,g,o from lanes 4n+1..3
            float fv = __shfl_down(a, 1);
            float gv = __shfl_down(a, 2);
            float ov = __shfl_down(a, 3);
            if (q == 0) {
                c = fv * c + a * gv;                 // c = f*c + i*g
                float e2 = __expf(-2.f * c);
                float th = 2.f / (1.f + e2) - 1.f;   // tanh(c)
                h_buf[nxt][n] = ov * th;
            }
        }
        __syncthreads();
    }

    // ---- FC head: out[b] = h_T . W_fc + b_fc ----
    if (tid < HID) red[tid] = h_buf[TSTEPS & 1][tid] * W_fc[tid];
    __syncthreads();
    if (tid == 0) {
        float s = 0.f;
        #pragma unroll 4
        for (int i = 0; i < HID; ++i) s += red[i];
        out[b] = s + b_fc[0];
    }
}

extern "C" void kernel_launch(void* const* d_in, const int* in_sizes, int n_in,
                              void* d_out, int out_size, void* d_ws, size_t ws_size,
                              hipStream_t stream) {
    const float* x    = (const float*)d_in[0];
    const float* h0   = (const float*)d_in[1];
    const float* c0   = (const float*)d_in[2];
    const float* W_ih = (const float*)d_in[3];
    const float* W_hh = (const float*)d_in[4];
    const float* b_ih = (const float*)d_in[5];
    const float* b_hh = (const float*)d_in[6];
    const float* W_fc = (const float*)d_in[7];
    const float* b_fc = (const float*)d_in[8];
    float* out = (float*)d_out;

    lstm_fused_kernel<<<dim3(BATCH), dim3(BLOCK), 0, stream>>>(
        x, h0, c0, W_ih, W_hh, b_ih, b_hh, W_fc, b_fc, out);
}

// Round 2
// 1059.531 us; speedup vs baseline: 1.0566x; 1.0566x over previous
//
#include <hip/hip_runtime.h>
#include <math.h>

#define BATCH 256
#define TSTEPS 1024
#define DIN 64
#define HID 100
#define GATES 400      // 4*HID
#define BLOCK 512
#define XT 32          // timesteps per x LDS tile

__global__ __launch_bounds__(BLOCK, 1)
void lstm_fused_kernel(const float* __restrict__ x, const float* __restrict__ h0,
                       const float* __restrict__ c0, const float* __restrict__ W_ih,
                       const float* __restrict__ W_hh, const float* __restrict__ b_ih,
                       const float* __restrict__ b_hh, const float* __restrict__ W_fc,
                       const float* __restrict__ b_fc, float* __restrict__ out)
{
    __shared__ __align__(16) float h_buf[2][104];   // double-buffered hidden state
    __shared__ __align__(16) float x_tile[XT * DIN];
    __shared__ float red[128];

    const int tid = threadIdx.x;
    const int b = blockIdx.x;
    const int q = tid & 3;        // gate type: 0=i 1=f 2=g 3=o
    const int n = tid >> 2;       // unit index
    const int g = q * HID + n;    // row in W_ih / W_hh
    const int gl = (tid < GATES) ? g : 0;   // clamped row: ALL threads load

    // ---- register-resident weights: W_ih row (64) + W_hh row (100) ----
    // Loads are UNCONDITIONAL (clamped row) and each value is pinned with an
    // asm tie so the compiler cannot sink the loads into the t-loop
    // (round-1 failure mode: VGPR_Count=100 -> weights re-fetched every step).
    float wih[DIN];
    float whh[HID];
    {
        const float4* wi4 = reinterpret_cast<const float4*>(W_ih + gl * DIN);
        #pragma unroll
        for (int k = 0; k < DIN / 4; ++k) {
            float4 v = wi4[k];
            wih[4*k+0] = v.x; wih[4*k+1] = v.y; wih[4*k+2] = v.z; wih[4*k+3] = v.w;
        }
        const float4* wh4 = reinterpret_cast<const float4*>(W_hh + gl * HID);
        #pragma unroll
        for (int k = 0; k < HID / 4; ++k) {
            float4 v = wh4[k];
            whh[4*k+0] = v.x; whh[4*k+1] = v.y; whh[4*k+2] = v.z; whh[4*k+3] = v.w;
        }
    }
    #pragma unroll
    for (int k = 0; k < DIN; ++k) asm volatile("" : "+v"(wih[k]));
    #pragma unroll
    for (int k = 0; k < HID; ++k) asm volatile("" : "+v"(whh[k]));

    const float bias = b_ih[gl] + b_hh[gl];

    // ---- init h, c ----
    if (tid < HID) h_buf[0][tid] = h0[b * HID + tid];
    float c = 0.f;
    if (q == 0 && n < HID) c = c0[b * HID + n];
    __syncthreads();

    for (int tt = 0; tt < TSTEPS; tt += XT) {
        // stage next 32 timesteps of x: 2048 floats = 512 float4, one per thread
        {
            const float4* xs = reinterpret_cast<const float4*>(
                x + (size_t)b * TSTEPS * DIN + (size_t)tt * DIN);
            reinterpret_cast<float4*>(x_tile)[tid] = xs[tid];
        }
        __syncthreads();

        #pragma unroll 2
        for (int t2 = 0; t2 < XT; ++t2) {
            const int t = tt + t2;
            const int cur = t & 1, nxt = cur ^ 1;

            float a0 = 0.f, a1 = 0.f, a2 = 0.f, a3 = 0.f;
            const float4* h4 = reinterpret_cast<const float4*>(h_buf[cur]);
            #pragma unroll
            for (int k = 0; k < HID / 4; ++k) {
                float4 hv = h4[k];             // broadcast LDS read (conflict-free)
                a0 += hv.x * whh[4*k+0];
                a1 += hv.y * whh[4*k+1];
                a2 += hv.z * whh[4*k+2];
                a3 += hv.w * whh[4*k+3];
            }
            const float4* x4 = reinterpret_cast<const float4*>(&x_tile[t2 * DIN]);
            #pragma unroll
            for (int k = 0; k < DIN / 4; ++k) {
                float4 xv = x4[k];             // broadcast LDS read (conflict-free)
                a0 += xv.x * wih[4*k+0];
                a1 += xv.y * wih[4*k+1];
                a2 += xv.z * wih[4*k+2];
                a3 += xv.w * wih[4*k+3];
            }
            float z = ((a0 + a1) + (a2 + a3)) + bias;

            // activation: q==2 -> tanh, else sigmoid (q is per-thread constant)
            float zq = (q == 2) ? 2.f * z : z;
            float e = __expf(-zq);
            float s = 1.f / (1.f + e);
            float a = (q == 2) ? (2.f * s - 1.f) : s;

            // quad exchange: lane 4n gathers f,g,o from lanes 4n+1..3
            float fv = __shfl_down(a, 1);
            float gv = __shfl_down(a, 2);
            float ov = __shfl_down(a, 3);
            if (q == 0 && n < HID) {
                c = fv * c + a * gv;                 // c = f*c + i*g
                float e2 = __expf(-2.f * c);
                float th = 2.f / (1.f + e2) - 1.f;   // tanh(c)
                h_buf[nxt][n] = ov * th;
            }
            __syncthreads();
        }
    }

    // ---- FC head: out[b] = h_T . W_fc + b_fc ----
    if (tid < HID) red[tid] = h_buf[0][tid] * W_fc[tid];   // TSTEPS even -> final h in buf 0
    __syncthreads();
    if (tid == 0) {
        float s = 0.f;
        #pragma unroll 4
        for (int i = 0; i < HID; ++i) s += red[i];
        out[b] = s + b_fc[0];
    }
}

extern "C" void kernel_launch(void* const* d_in, const int* in_sizes, int n_in,
                              void* d_out, int out_size, void* d_ws, size_t ws_size,
                              hipStream_t stream) {
    const float* x    = (const float*)d_in[0];
    const float* h0   = (const float*)d_in[1];
    const float* c0   = (const float*)d_in[2];
    const float* W_ih = (const float*)d_in[3];
    const float* W_hh = (const float*)d_in[4];
    const float* b_ih = (const float*)d_in[5];
    const float* b_hh = (const float*)d_in[6];
    const float* W_fc = (const float*)d_in[7];
    const float* b_fc = (const float*)d_in[8];
    float* out = (float*)d_out;

    lstm_fused_kernel<<<dim3(BATCH), dim3(BLOCK), 0, stream>>>(
        x, h0, c0, W_ih, W_hh, b_ih, b_hh, W_fc, b_fc, out);
}

// Round 3
// 927.166 us; speedup vs baseline: 1.2074x; 1.1428x over previous
//
#include <hip/hip_runtime.h>
#include <math.h>

#define BATCH 256
#define TSTEPS 1024
#define DIN 64
#define HID 100
#define BLOCK 832     // 800 gate threads (2 per gate row) + pad to 13 waves
#define XT 32         // timesteps per x LDS tile

// Thread layout: tid = 8*n + 2*q + p
//   n = unit (0..99 real, 100..103 pad), q = gate (i,f,g,o), p = k-half
// Unit n's 8 threads are lanes 8n..8n+7 -> all intra-wave shuffles.
// p=0 covers W_hh cols 0..51, W_ih cols 0..31; p=1 covers 48..99 (first 4 zeroed), 32..63.

__global__ __launch_bounds__(BLOCK, 1)
void lstm_fused_kernel(const float* __restrict__ x, const float* __restrict__ h0,
                       const float* __restrict__ c0, const float* __restrict__ W_ih,
                       const float* __restrict__ W_hh, const float* __restrict__ b_ih,
                       const float* __restrict__ b_hh, const float* __restrict__ W_fc,
                       const float* __restrict__ b_fc, float* __restrict__ out)
{
    __shared__ __align__(16) float h_buf[2][104];   // double-buffered hidden state
    __shared__ __align__(16) float x_tile[XT * DIN];
    __shared__ float red[128];

    const int tid = threadIdx.x;
    const int b = blockIdx.x;
    const int p  = tid & 1;
    const int gq = tid >> 1;          // 0..415
    const int q  = gq & 3;            // gate: 0=i 1=f 2=g 3=o
    const int n  = gq >> 2;           // unit 0..103 (>=100 is pad)
    const int nl = (n < HID) ? n : (HID - 1);
    const int gl = q * HID + nl;      // clamped weight row

    const int cb  = p * 48;           // W_hh col base (52 cols each, 4-col overlap)
    const int cb2 = p * 32;           // W_ih col base

    // ---- register-resident half-rows: 52 + 32 = 84 floats/thread ----
    float whh[52];
    #pragma unroll
    for (int j = 0; j < 52; ++j) whh[j] = W_hh[gl * HID + cb + j];
    if (p) { whh[0] = 0.f; whh[1] = 0.f; whh[2] = 0.f; whh[3] = 0.f; } // overlap cols belong to p=0
    float wih[32];
    #pragma unroll
    for (int j = 0; j < 32; ++j) wih[j] = W_ih[gl * DIN + cb2 + j];
    #pragma unroll
    for (int j = 0; j < 52; ++j) asm volatile("" : "+v"(whh[j]));
    #pragma unroll
    for (int j = 0; j < 32; ++j) asm volatile("" : "+v"(wih[j]));

    const float bias = (p == 0) ? (b_ih[gl] + b_hh[gl]) : 0.f;

    // activation constants: q==2 -> tanh(z)=1-2/(1+e^{2z}); else sigmoid(z)=1/(1+e^{-z})
    const float mQ = (q == 2) ?  2.f : -1.f;
    const float aQ = (q == 2) ?  1.f :  0.f;
    const float bQ = (q == 2) ? -2.f :  1.f;

    // ---- init h, c ----
    if (tid < HID) h_buf[0][tid] = h0[b * HID + tid];
    float c = 0.f;
    if ((tid & 7) == 0) c = c0[b * HID + nl];
    __syncthreads();

    for (int tt = 0; tt < TSTEPS; tt += XT) {
        if (tid < 512) {
            const float4* xs = reinterpret_cast<const float4*>(
                x + (size_t)b * TSTEPS * DIN + (size_t)tt * DIN);
            reinterpret_cast<float4*>(x_tile)[tid] = xs[tid];
        }
        __syncthreads();

        #pragma unroll 2
        for (int t2 = 0; t2 < XT; ++t2) {
            const int cur = (tt + t2) & 1, nxt = cur ^ 1;

            float a0 = 0.f, a1 = 0.f, a2 = 0.f, a3 = 0.f;
            const float4* h4 = reinterpret_cast<const float4*>(&h_buf[cur][cb]);
            #pragma unroll
            for (int k = 0; k < 13; ++k) {         // broadcast LDS reads (2-way: free)
                float4 hv = h4[k];
                a0 += hv.x * whh[4*k+0];
                a1 += hv.y * whh[4*k+1];
                a2 += hv.z * whh[4*k+2];
                a3 += hv.w * whh[4*k+3];
            }
            const float4* x4 = reinterpret_cast<const float4*>(&x_tile[t2 * DIN + cb2]);
            #pragma unroll
            for (int k = 0; k < 8; ++k) {
                float4 xv = x4[k];
                a0 += xv.x * wih[4*k+0];
                a1 += xv.y * wih[4*k+1];
                a2 += xv.z * wih[4*k+2];
                a3 += xv.w * wih[4*k+3];
            }
            float sum = ((a0 + a1) + (a2 + a3)) + bias;
            float z = sum + __shfl_xor(sum, 1);     // pair k-reduce: both halves get full z

            float e = __expf(mQ * z);
            float s = __builtin_amdgcn_rcpf(1.f + e);
            float a = fmaf(bQ, s, aQ);              // sigmoid or tanh per q

            // unit-quad gather to owner lane 8n: f@+2, g@+4, o@+6
            float fv = __shfl_down(a, 2);
            float gv = __shfl_down(a, 4);
            float ov = __shfl_down(a, 6);
            if ((tid & 7) == 0) {
                c = fmaf(fv, c, a * gv);            // c = f*c + i*g
                float e2 = __expf(c + c);
                float th = fmaf(-2.f, __builtin_amdgcn_rcpf(1.f + e2), 1.f); // tanh(c)
                h_buf[nxt][n] = ov * th;            // n>=100 lands in padding
            }
            __syncthreads();
        }
    }

    // ---- FC head: out[b] = h_T . W_fc + b_fc (TSTEPS even -> final h in buf 0) ----
    if (tid < HID) red[tid] = h_buf[0][tid] * W_fc[tid];
    __syncthreads();
    if (tid == 0) {
        float sfc = 0.f;
        #pragma unroll 4
        for (int i = 0; i < HID; ++i) sfc += red[i];
        out[b] = sfc + b_fc[0];
    }
}

extern "C" void kernel_launch(void* const* d_in, const int* in_sizes, int n_in,
                              void* d_out, int out_size, void* d_ws, size_t ws_size,
                              hipStream_t stream) {
    const float* x    = (const float*)d_in[0];
    const float* h0   = (const float*)d_in[1];
    const float* c0   = (const float*)d_in[2];
    const float* W_ih = (const float*)d_in[3];
    const float* W_hh = (const float*)d_in[4];
    const float* b_ih = (const float*)d_in[5];
    const float* b_hh = (const float*)d_in[6];
    const float* W_fc = (const float*)d_in[7];
    const float* b_fc = (const float*)d_in[8];
    float* out = (float*)d_out;

    lstm_fused_kernel<<<dim3(BATCH), dim3(BLOCK), 0, stream>>>(
        x, h0, c0, W_ih, W_hh, b_ih, b_hh, W_fc, b_fc, out);
}